// Round 6
// baseline (207.689 us; speedup 1.0000x reference)
//
#include <hip/hip_runtime.h>
#include <hip/hip_bf16.h>

typedef __bf16 bf16x8_t __attribute__((ext_vector_type(8)));
typedef float  f32x4_t  __attribute__((ext_vector_type(4)));
typedef short  short8_t __attribute__((ext_vector_type(8)));
typedef short  short4_t __attribute__((ext_vector_type(4)));

#define NB   4
#define NH   16
#define SEQ  2048
#define HD   64
#define QT   64    // q rows per run; block runs two q-tiles sequentially (31-z, then z)
#define BKV  64
#define NQT  (SEQ / QT)   // 32 q-tiles
#define LSTR 72    // LDS row stride in bf16 elems: 144B rows, 16B-aligned blocks

// masked score in base-2 domain: WHERE_CONST * log2(e)
#define MASK2 (-14426.950408889634f)
// softmax scale folded into Q: (1/sqrt(64)) * log2(e)
#define QSCL  (0.18033688011112042f)

// uniform swizzled LDS address (shorts): row*72 + ((blk ^ (row>>3)) & 7) * 8
__device__ __forceinline__ int swz(int rowi, int blk) {
    return rowi * LSTR + (((blk) ^ (rowi >> 3)) & 7) * 8;
}

__global__ void __launch_bounds__(256)
fa_fwd(const float* __restrict__ qg,
       const float* __restrict__ kg,
       const float* __restrict__ vg,
       float* __restrict__ outg) {
    __shared__ alignas(16) short k_lds[BKV * LSTR];   // K tile bf16 [kv][d], block-swizzled
    __shared__ alignas(16) short vt_lds[HD * LSTR];   // V^T tile bf16 [d][kv], block-swizzled
    __shared__ alignas(16) short p_lds[QT * LSTR];    // P bf16 [q][kv], block-swizzled

    const int tid  = threadIdx.x;
    const int wave = tid >> 6;
    const int lane = tid & 63;
    const int l16  = lane & 15;
    const int quad = lane >> 4;

    // grid: x = bh (64), y = z (16). Block z runs q-tiles (31-z) then (z):
    // shells = (32-z) + (z+1) = 33 for EVERY block -> perfectly uniform, 1024 blocks.
    const int bh = blockIdx.x;
    const int z  = blockIdx.y;

    const size_t base = (size_t)bh * SEQ * HD;
    const float* qp = qg + base;
    const float* kp = kg + base;
    const float* vp = vg + base;

    // ---- staging addressing: thread owns kv rows 4*sr..4*sr+3, d block d0..d0+3 ----
    const int sr = tid >> 4;      // 0..15
    const int cb = tid & 15;
    const int d0 = cb * 4;

    f32x4_t kreg[4], vreg[4];     // tile data in flight during compute

    auto issue = [&](int kt0) {
        const float* kr = kp + (size_t)(kt0 + 4 * sr) * HD + d0;
        const float* vr = vp + (size_t)(kt0 + 4 * sr) * HD + d0;
        #pragma unroll
        for (int i = 0; i < 4; ++i) {
            kreg[i] = *(const f32x4_t*)(kr + i * HD);
            vreg[i] = *(const f32x4_t*)(vr + i * HD);
        }
    };

    auto stage = [&]() {
        #pragma unroll
        for (int i = 0; i < 4; ++i) {
            const int r0 = 4 * sr + i;
            short4_t kw;
            #pragma unroll
            for (int j = 0; j < 4; ++j) kw[j] = __builtin_bit_cast(short, (__bf16)kreg[i][j]);
            *(short4_t*)&k_lds[swz(r0, cb >> 1) + (cb & 1) * 4] = kw;
        }
        #pragma unroll
        for (int j = 0; j < 4; ++j) {
            short4_t vw;
            #pragma unroll
            for (int i = 0; i < 4; ++i) vw[i] = __builtin_bit_cast(short, (__bf16)vreg[i][j]);
            *(short4_t*)&vt_lds[swz(d0 + j, sr >> 1) + (sr & 1) * 4] = vw;
        }
    };

    const int qloc = wave * 16 + l16;   // diag-tile local q row
    const int b = bh >> 4;
    const int h = bh & 15;
    const f32x4_t zero4 = {0.0f, 0.0f, 0.0f, 0.0f};

    issue(0);   // prologue: run-0 tile 0 in flight

    #pragma unroll 1
    for (int run = 0; run < 2; ++run) {
        const int qt = (run == 0) ? (NQT - 1 - z) : z;
        const int q0 = qt * QT;
        const int nt = qt + 1;            // KV tiles this run needs

        // ---- Q fragments (B-operand in swapped QK^T): q=l16-row, d=quad*8+j ----
        bf16x8_t qf0, qf1;
        {
            const float* qr = qp + (size_t)(q0 + wave * 16 + l16) * HD;
            f32x4_t a0 = *(const f32x4_t*)(qr + quad * 8);
            f32x4_t a1 = *(const f32x4_t*)(qr + quad * 8 + 4);
            f32x4_t a2 = *(const f32x4_t*)(qr + 32 + quad * 8);
            f32x4_t a3 = *(const f32x4_t*)(qr + 32 + quad * 8 + 4);
            #pragma unroll
            for (int j = 0; j < 4; ++j) {
                qf0[j]     = (__bf16)(a0[j] * QSCL);
                qf0[4 + j] = (__bf16)(a1[j] * QSCL);
                qf1[j]     = (__bf16)(a2[j] * QSCL);
                qf1[4 + j] = (__bf16)(a3[j] * QSCL);
            }
        }

        f32x4_t o_acc[4];
        #pragma unroll
        for (int c = 0; c < 4; ++c) o_acc[c] = zero4;
        float m_x = MASK2, l_x = 0.0f;

        #pragma unroll 1
        for (int t = 0; t < nt; ++t) {
            const int kt0 = t * BKV;
            __syncthreads();            // prior LDS readers done (also covers run switch)
            stage();                    // regs (tile t) -> LDS, bf16 convert
            __syncthreads();            // staged tile visible
            if (t + 1 < nt) issue(kt0 + BKV);       // next tile in flight during compute
            else if (run == 0) issue(0);            // prefetch run-1 tile 0

            // ---- S^T = K Q^T : D[m=kv][n=q];  kv = c*16+quad*4+r, q = l16 ----
            f32x4_t s_acc[4];
            #pragma unroll
            for (int c = 0; c < 4; ++c) s_acc[c] = zero4;
            __builtin_amdgcn_s_setprio(1);
            #pragma unroll
            for (int c = 0; c < 4; ++c) {
                const int kvrow = c * 16 + l16;
                bf16x8_t kf0 = __builtin_bit_cast(bf16x8_t, *(const short8_t*)&k_lds[swz(kvrow, quad)]);
                bf16x8_t kf1 = __builtin_bit_cast(bf16x8_t, *(const short8_t*)&k_lds[swz(kvrow, quad + 4)]);
                s_acc[c] = __builtin_amdgcn_mfma_f32_16x16x32_bf16(kf0, qf0, s_acc[c], 0, 0, 0);
                s_acc[c] = __builtin_amdgcn_mfma_f32_16x16x32_bf16(kf1, qf1, s_acc[c], 0, 0, 0);
            }
            __builtin_amdgcn_s_setprio(0);

            // ---- online softmax: all 16 values belong to this lane's q row ----
            float sv[4][4];
            float vmax = MASK2;
            const bool diag = (t == nt - 1);
            #pragma unroll
            for (int c = 0; c < 4; ++c) {
                #pragma unroll
                for (int r = 0; r < 4; ++r) {
                    float x = s_acc[c][r];
                    if (diag && (c * 16 + quad * 4 + r > qloc)) x = MASK2;
                    sv[c][r] = x;
                    vmax = fmaxf(vmax, x);
                }
            }
            vmax = fmaxf(vmax, __shfl_xor(vmax, 16));
            vmax = fmaxf(vmax, __shfl_xor(vmax, 32));

            if (__any((int)(vmax > m_x))) {
                float mn = fmaxf(m_x, vmax);
                float a  = __builtin_amdgcn_exp2f(m_x - mn);   // arg <= 0
                m_x = mn;
                l_x *= a;
                float ar[4];
                #pragma unroll
                for (int r = 0; r < 4; ++r)
                    ar[r] = __shfl(a, (lane & 48) | (quad * 4 + r));   // alpha of o_acc's row
                #pragma unroll
                for (int c = 0; c < 4; ++c)
                    #pragma unroll
                    for (int r = 0; r < 4; ++r)
                        o_acc[c][r] *= ar[r];
            }

            // ---- P = exp2(sv - m); row sum; write P (4 contiguous kv per c -> 8B) ----
            const int prow = wave * 16 + l16;
            float rs = 0.0f;
            #pragma unroll
            for (int c = 0; c < 4; ++c) {
                short4_t pw;
                #pragma unroll
                for (int r = 0; r < 4; ++r) {
                    float p = __builtin_amdgcn_exp2f(sv[c][r] - m_x);  // arg <= 0
                    rs += p;
                    pw[r] = __builtin_bit_cast(short, (__bf16)p);
                }
                *(short4_t*)&p_lds[swz(prow, 2 * c + (quad >> 1)) + (quad & 1) * 4] = pw;
            }
            rs += __shfl_xor(rs, 16);
            rs += __shfl_xor(rs, 32);
            l_x += rs;

            // NO barrier: P tile written and read within the same wave (lgkmcnt orders)

            // ---- O += P V  (A = P[m=q][k=kv], B = V^T rows as B[k=kv][n=d]) ----
            bf16x8_t pf0 = __builtin_bit_cast(bf16x8_t, *(const short8_t*)&p_lds[swz(prow, quad)]);
            bf16x8_t pf1 = __builtin_bit_cast(bf16x8_t, *(const short8_t*)&p_lds[swz(prow, quad + 4)]);
            __builtin_amdgcn_s_setprio(1);
            #pragma unroll
            for (int c = 0; c < 4; ++c) {
                const int d = c * 16 + l16;
                bf16x8_t b0 = __builtin_bit_cast(bf16x8_t, *(const short8_t*)&vt_lds[swz(d, quad)]);
                bf16x8_t b1 = __builtin_bit_cast(bf16x8_t, *(const short8_t*)&vt_lds[swz(d, quad + 4)]);
                o_acc[c] = __builtin_amdgcn_mfma_f32_16x16x32_bf16(pf0, b0, o_acc[c], 0, 0, 0);
                o_acc[c] = __builtin_amdgcn_mfma_f32_16x16x32_bf16(pf1, b1, o_acc[c], 0, 0, 0);
            }
            __builtin_amdgcn_s_setprio(0);
        }

        // ---- epilogue for this run: O / l, fp32 store to out[b][q][h*64 + d] ----
        #pragma unroll
        for (int r = 0; r < 4; ++r) {
            const float lr = __shfl(l_x, (lane & 48) | (quad * 4 + r));
            const float inv_l = 1.0f / fmaxf(lr, 1e-30f);
            const int row = q0 + wave * 16 + quad * 4 + r;
            float* op = outg + ((size_t)b * SEQ + row) * (NH * HD) + h * HD;
            #pragma unroll
            for (int c = 0; c < 4; ++c) {
                float val = o_acc[c][r] * inv_l;
                unsigned bits = __builtin_bit_cast(unsigned, val);
                if ((bits & 0x7F800000u) == 0x7F800000u) val = 0.0f;  // scrub inf/NaN
                op[c * 16 + l16] = val;
            }
        }
    }
}

extern "C" void kernel_launch(void* const* d_in, const int* in_sizes, int n_in,
                              void* d_out, int out_size, void* d_ws, size_t ws_size,
                              hipStream_t stream) {
    const float* q = (const float*)d_in[0];
    const float* k = (const float*)d_in[1];
    const float* v = (const float*)d_in[2];
    float* out = (float*)d_out;
    dim3 grid(NB * NH, NQT / 2);   // 1024 uniform blocks: each = 33 shell-iterations
    fa_fwd<<<grid, 256, 0, stream>>>(q, k, v, out);
}

// Round 8
// 201.167 us; speedup vs baseline: 1.0324x; 1.0324x over previous
//
#include <hip/hip_runtime.h>
#include <hip/hip_bf16.h>

typedef __bf16 bf16x8_t __attribute__((ext_vector_type(8)));
typedef float  f32x4_t  __attribute__((ext_vector_type(4)));
typedef short  short8_t __attribute__((ext_vector_type(8)));
typedef short  short4_t __attribute__((ext_vector_type(4)));
typedef unsigned short ushort4_t __attribute__((ext_vector_type(4)));

typedef const __attribute__((address_space(1))) unsigned int* gptr_t;
typedef __attribute__((address_space(3))) unsigned int* lptr_t;

#define NB   4
#define NH   16
#define SEQ  2048
#define HD   64
#define BQ   64
#define BKV  64
#define NT   (SEQ / BKV)          // 32 kv tiles per bh
#define TILE_SH (BKV * HD)        // 4096 shorts = 8KB per image tile

// masked score in base-2 domain: WHERE_CONST * log2(e)
#define MASK2 (-14426.950408889634f)
// softmax scale folded into Q: (1/sqrt(64)) * log2(e)
#define QSCL  (0.18033688011112042f)

// 64x64 bf16 tile, 128B rows, 16B-block XOR swizzle (index in shorts).
// Same function used by the pre-pass (image write) and the main kernel (LDS read),
// so global_load_lds can copy the image LINEARLY into LDS (rule: linear dest +
// pre-swizzled source + swizzled read).
__device__ __forceinline__ int xaddr(int row, int blk) {
    return row * 64 + (((blk ^ row) & 7) << 3);
}

// ---------------- pre-pass: fp32 K,V  ->  bf16 swizzled tile images ----------------
__global__ void __launch_bounds__(256)
prep_kv(const float* __restrict__ kg, const float* __restrict__ vg,
        unsigned short* __restrict__ kimg, unsigned short* __restrict__ vimg) {
    const int t   = blockIdx.x;       // kv tile
    const int bh  = blockIdx.y;
    const int tid = threadIdx.x;
    const int sr  = tid >> 4;         // owns kv rows 4sr..4sr+3
    const int cb  = tid & 15;         // d block
    const int d0  = cb * 4;

    const size_t gbase = ((size_t)bh * SEQ + (size_t)t * BKV) * HD;
    const size_t ibase = ((size_t)bh * NT + t) * TILE_SH;

    f32x4_t v4[4];
    #pragma unroll
    for (int i = 0; i < 4; ++i) {
        const int r = 4 * sr + i;
        f32x4_t k4 = *(const f32x4_t*)(kg + gbase + (size_t)r * HD + d0);
        v4[i]      = *(const f32x4_t*)(vg + gbase + (size_t)r * HD + d0);
        ushort4_t kw;
        #pragma unroll
        for (int j = 0; j < 4; ++j) kw[j] = __builtin_bit_cast(unsigned short, (__bf16)k4[j]);
        // K image: [kv row][d], 4 consecutive d = one aligned 8B chunk
        *(ushort4_t*)&kimg[ibase + xaddr(r, cb >> 1) + (cb & 1) * 4] = kw;
    }
    // V^T image: [d row][kv]; register-transpose 4x4 -> 4 contiguous kv = 8B chunks
    #pragma unroll
    for (int j = 0; j < 4; ++j) {
        ushort4_t vw;
        #pragma unroll
        for (int i = 0; i < 4; ++i) vw[i] = __builtin_bit_cast(unsigned short, (__bf16)v4[i][j]);
        *(ushort4_t*)&vimg[ibase + xaddr(d0 + j, sr >> 1) + (sr & 1) * 4] = vw;
    }
}

// async 16B global->LDS copy; lds base wave-uniform (HW adds lane*16B), g per-lane
__device__ __forceinline__ void gl16(const unsigned short* g, short* l) {
    __builtin_amdgcn_global_load_lds((gptr_t)g, (lptr_t)l, 16, 0, 0);
}

// ---------------- main kernel: images -> LDS via global_load_lds ----------------
__global__ void __launch_bounds__(256)
fa_fwd(const float* __restrict__ qg,
       const unsigned short* __restrict__ kimg,
       const unsigned short* __restrict__ vimg,
       float* __restrict__ outg) {
    __shared__ alignas(16) short kv_lds[2][2][TILE_SH];  // [buf][K/V][4096] = 32KB
    __shared__ alignas(16) short p_lds[64 * 64];         // P bf16, 8KB, same swizzle

    const int tid  = threadIdx.x;
    const int wave = tid >> 6;
    const int lane = tid & 63;
    const int l16  = lane & 15;
    const int quad = lane >> 4;

    // grid: x = bh (64), y = q-tile (32), reversed so heavy blocks dispatch first
    const int bh = blockIdx.x;
    const int qt = (int)gridDim.y - 1 - (int)blockIdx.y;
    const int q0 = qt * BQ;

    const float* qp = qg + (size_t)bh * SEQ * HD;
    const unsigned short* kb = kimg + (size_t)bh * NT * TILE_SH;
    const unsigned short* vb = vimg + (size_t)bh * NT * TILE_SH;

    // ---- Q fragments (B-operand in swapped QK^T): q=l16-row, d=quad*8+j ----
    bf16x8_t qf0, qf1;
    {
        const float* qr = qp + (size_t)(q0 + wave * 16 + l16) * HD;
        f32x4_t a0 = *(const f32x4_t*)(qr + quad * 8);
        f32x4_t a1 = *(const f32x4_t*)(qr + quad * 8 + 4);
        f32x4_t a2 = *(const f32x4_t*)(qr + 32 + quad * 8);
        f32x4_t a3 = *(const f32x4_t*)(qr + 32 + quad * 8 + 4);
        #pragma unroll
        for (int j = 0; j < 4; ++j) {
            qf0[j]     = (__bf16)(a0[j] * QSCL);
            qf0[4 + j] = (__bf16)(a1[j] * QSCL);
            qf1[j]     = (__bf16)(a2[j] * QSCL);
            qf1[4 + j] = (__bf16)(a3[j] * QSCL);
        }
    }

    f32x4_t o_acc[4];
    const f32x4_t zero4 = {0.0f, 0.0f, 0.0f, 0.0f};
    #pragma unroll
    for (int c = 0; c < 4; ++c) o_acc[c] = zero4;
    float m_x = MASK2, l_x = 0.0f;

    // staging: 2 rounds x (K,V) of 16B per thread; image is already LDS-layout
    auto stage = [&](int buf, int t) {
        const unsigned short* kg_ = kb + (size_t)t * TILE_SH;
        const unsigned short* vg_ = vb + (size_t)t * TILE_SH;
        #pragma unroll
        for (int r = 0; r < 2; ++r) {
            const int loff = r * 2048 + wave * 512;      // wave-uniform (shorts)
            const int goff = loff + lane * 8;            // per-lane (shorts)
            gl16(kg_ + goff, &kv_lds[buf][0][loff]);
            gl16(vg_ + goff, &kv_lds[buf][1][loff]);
        }
    };

    const int qloc = wave * 16 + l16;   // diag-tile local q row
    const int nt = qt + 1;
    int cur = 0;

    stage(0, 0);   // prologue: tile 0 in flight

    #pragma unroll 1
    for (int t = 0; t < nt; ++t) {
        // one barrier per iter: implicit vmcnt(0) drain completes buf[cur]'s
        // global_load_lds AND guarantees buf[cur^1]'s readers (iter t-1) are done.
        __syncthreads();
        if (t + 1 < nt) stage(cur ^ 1, t + 1);   // next tile flies during compute

        const short* kt_ = kv_lds[cur][0];
        const short* vt_ = kv_lds[cur][1];

        // ---- S^T = K Q^T : D[m=kv][n=q];  kv = c*16+quad*4+r, q = l16 ----
        f32x4_t s_acc[4];
        #pragma unroll
        for (int c = 0; c < 4; ++c) s_acc[c] = zero4;
        __builtin_amdgcn_s_setprio(1);
        #pragma unroll
        for (int c = 0; c < 4; ++c) {
            const int kvrow = c * 16 + l16;
            bf16x8_t kf0 = __builtin_bit_cast(bf16x8_t, *(const short8_t*)&kt_[xaddr(kvrow, quad)]);
            bf16x8_t kf1 = __builtin_bit_cast(bf16x8_t, *(const short8_t*)&kt_[xaddr(kvrow, quad + 4)]);
            s_acc[c] = __builtin_amdgcn_mfma_f32_16x16x32_bf16(kf0, qf0, s_acc[c], 0, 0, 0);
            s_acc[c] = __builtin_amdgcn_mfma_f32_16x16x32_bf16(kf1, qf1, s_acc[c], 0, 0, 0);
        }
        __builtin_amdgcn_s_setprio(0);

        // ---- online softmax: all 16 values belong to this lane's q row ----
        float sv[4][4];
        float vmax = MASK2;
        const bool diag = (t == nt - 1);
        #pragma unroll
        for (int c = 0; c < 4; ++c) {
            #pragma unroll
            for (int r = 0; r < 4; ++r) {
                float x = s_acc[c][r];
                if (diag && (c * 16 + quad * 4 + r > qloc)) x = MASK2;
                sv[c][r] = x;
                vmax = fmaxf(vmax, x);
            }
        }
        vmax = fmaxf(vmax, __shfl_xor(vmax, 16));
        vmax = fmaxf(vmax, __shfl_xor(vmax, 32));

        if (__any((int)(vmax > m_x))) {
            float mn = fmaxf(m_x, vmax);
            float a  = __builtin_amdgcn_exp2f(m_x - mn);   // arg <= 0
            m_x = mn;
            l_x *= a;
            float ar[4];
            #pragma unroll
            for (int r = 0; r < 4; ++r)
                ar[r] = __shfl(a, (lane & 48) | (quad * 4 + r));   // alpha of o_acc's row
            #pragma unroll
            for (int c = 0; c < 4; ++c)
                #pragma unroll
                for (int r = 0; r < 4; ++r)
                    o_acc[c][r] *= ar[r];
        }

        // ---- P = exp2(sv - m); row sum; write P (4 contiguous kv -> 8B writes) ----
        const int prow = wave * 16 + l16;
        float rs = 0.0f;
        #pragma unroll
        for (int c = 0; c < 4; ++c) {
            short4_t pw;
            #pragma unroll
            for (int r = 0; r < 4; ++r) {
                float p = __builtin_amdgcn_exp2f(sv[c][r] - m_x);  // arg <= 0
                rs += p;
                pw[r] = __builtin_bit_cast(short, (__bf16)p);
            }
            *(short4_t*)&p_lds[xaddr(prow, 2 * c + (quad >> 1)) + (quad & 1) * 4] = pw;
        }
        rs += __shfl_xor(rs, 16);
        rs += __shfl_xor(rs, 32);
        l_x += rs;

        // NO barrier: P tile written and read within the same wave (lgkmcnt orders)

        // ---- O += P V  (A = P[m=q][k=kv], B = V^T rows as B[k=kv][n=d]) ----
        bf16x8_t pf0 = __builtin_bit_cast(bf16x8_t, *(const short8_t*)&p_lds[xaddr(prow, quad)]);
        bf16x8_t pf1 = __builtin_bit_cast(bf16x8_t, *(const short8_t*)&p_lds[xaddr(prow, quad + 4)]);
        __builtin_amdgcn_s_setprio(1);
        #pragma unroll
        for (int c = 0; c < 4; ++c) {
            const int d = c * 16 + l16;
            bf16x8_t b0 = __builtin_bit_cast(bf16x8_t, *(const short8_t*)&vt_[xaddr(d, quad)]);
            bf16x8_t b1 = __builtin_bit_cast(bf16x8_t, *(const short8_t*)&vt_[xaddr(d, quad + 4)]);
            o_acc[c] = __builtin_amdgcn_mfma_f32_16x16x32_bf16(pf0, b0, o_acc[c], 0, 0, 0);
            o_acc[c] = __builtin_amdgcn_mfma_f32_16x16x32_bf16(pf1, b1, o_acc[c], 0, 0, 0);
        }
        __builtin_amdgcn_s_setprio(0);

        cur ^= 1;
    }

    // ---- epilogue: O / l, fp32 store to out[b][q][h*64 + d] ----
    const int b = bh >> 4;
    const int h = bh & 15;
    #pragma unroll
    for (int r = 0; r < 4; ++r) {
        const float lr = __shfl(l_x, (lane & 48) | (quad * 4 + r));
        const float inv_l = 1.0f / fmaxf(lr, 1e-30f);
        const int row = q0 + wave * 16 + quad * 4 + r;
        float* op = outg + ((size_t)b * SEQ + row) * (NH * HD) + h * HD;
        #pragma unroll
        for (int c = 0; c < 4; ++c) {
            float val = o_acc[c][r] * inv_l;
            unsigned bits = __builtin_bit_cast(unsigned, val);
            if ((bits & 0x7F800000u) == 0x7F800000u) val = 0.0f;  // scrub inf/NaN
            op[c * 16 + l16] = val;
        }
    }
}

// ---------------- fallback (no workspace): proven R2 kernel, fp32 staging ----------------
#define LSTR 72
__device__ __forceinline__ int swz(int rowi, int blk) {
    return rowi * LSTR + (((blk) ^ (rowi >> 3)) & 7) * 8;
}

__global__ void __launch_bounds__(256)
fa_fwd_fb(const float* __restrict__ qg,
          const float* __restrict__ kg,
          const float* __restrict__ vg,
          float* __restrict__ outg) {
    __shared__ alignas(16) short k_lds[BKV * LSTR];
    __shared__ alignas(16) short vt_lds[HD * LSTR];
    __shared__ alignas(16) short p_lds2[BQ * LSTR];

    const int tid  = threadIdx.x;
    const int wave = tid >> 6;
    const int lane = tid & 63;
    const int l16  = lane & 15;
    const int quad = lane >> 4;

    const int bh = blockIdx.x;
    const int qt = (int)gridDim.y - 1 - (int)blockIdx.y;
    const int q0 = qt * BQ;

    const size_t base = (size_t)bh * SEQ * HD;
    const float* qp = qg + base;
    const float* kp = kg + base;
    const float* vp = vg + base;

    bf16x8_t qf0, qf1;
    {
        const float* qr = qp + (size_t)(q0 + wave * 16 + l16) * HD;
        f32x4_t a0 = *(const f32x4_t*)(qr + quad * 8);
        f32x4_t a1 = *(const f32x4_t*)(qr + quad * 8 + 4);
        f32x4_t a2 = *(const f32x4_t*)(qr + 32 + quad * 8);
        f32x4_t a3 = *(const f32x4_t*)(qr + 32 + quad * 8 + 4);
        #pragma unroll
        for (int j = 0; j < 4; ++j) {
            qf0[j]     = (__bf16)(a0[j] * QSCL);
            qf0[4 + j] = (__bf16)(a1[j] * QSCL);
            qf1[j]     = (__bf16)(a2[j] * QSCL);
            qf1[4 + j] = (__bf16)(a3[j] * QSCL);
        }
    }

    f32x4_t o_acc[4];
    const f32x4_t zero4 = {0.0f, 0.0f, 0.0f, 0.0f};
    #pragma unroll
    for (int c = 0; c < 4; ++c) o_acc[c] = zero4;
    float m_x = MASK2, l_x = 0.0f;

    const int sr = tid >> 4;
    const int cb = tid & 15;
    const int d0 = cb * 4;
    f32x4_t kreg[4], vreg[4];

    auto issue = [&](int kt0) {
        const float* kr = kp + (size_t)(kt0 + 4 * sr) * HD + d0;
        const float* vr = vp + (size_t)(kt0 + 4 * sr) * HD + d0;
        #pragma unroll
        for (int i = 0; i < 4; ++i) {
            kreg[i] = *(const f32x4_t*)(kr + i * HD);
            vreg[i] = *(const f32x4_t*)(vr + i * HD);
        }
    };
    auto stg = [&]() {
        #pragma unroll
        for (int i = 0; i < 4; ++i) {
            const int r0 = 4 * sr + i;
            short4_t kw;
            #pragma unroll
            for (int j = 0; j < 4; ++j) kw[j] = __builtin_bit_cast(short, (__bf16)kreg[i][j]);
            *(short4_t*)&k_lds[swz(r0, cb >> 1) + (cb & 1) * 4] = kw;
        }
        #pragma unroll
        for (int j = 0; j < 4; ++j) {
            short4_t vw;
            #pragma unroll
            for (int i = 0; i < 4; ++i) vw[i] = __builtin_bit_cast(short, (__bf16)vreg[i][j]);
            *(short4_t*)&vt_lds[swz(d0 + j, sr >> 1) + (sr & 1) * 4] = vw;
        }
    };

    issue(0);
    const int qloc = wave * 16 + l16;
    const int nt = qt + 1;
    for (int t = 0; t < nt; ++t) {
        __syncthreads();
        stg();
        __syncthreads();
        if (t + 1 < nt) issue((t + 1) * BKV);

        f32x4_t s_acc[4];
        #pragma unroll
        for (int c = 0; c < 4; ++c) s_acc[c] = zero4;
        #pragma unroll
        for (int c = 0; c < 4; ++c) {
            const int kvrow = c * 16 + l16;
            bf16x8_t kf0 = __builtin_bit_cast(bf16x8_t, *(const short8_t*)&k_lds[swz(kvrow, quad)]);
            bf16x8_t kf1 = __builtin_bit_cast(bf16x8_t, *(const short8_t*)&k_lds[swz(kvrow, quad + 4)]);
            s_acc[c] = __builtin_amdgcn_mfma_f32_16x16x32_bf16(kf0, qf0, s_acc[c], 0, 0, 0);
            s_acc[c] = __builtin_amdgcn_mfma_f32_16x16x32_bf16(kf1, qf1, s_acc[c], 0, 0, 0);
        }

        float sv[4][4];
        float vmax = MASK2;
        const bool diag = (t == nt - 1);
        #pragma unroll
        for (int c = 0; c < 4; ++c)
            #pragma unroll
            for (int r = 0; r < 4; ++r) {
                float x = s_acc[c][r];
                if (diag && (c * 16 + quad * 4 + r > qloc)) x = MASK2;
                sv[c][r] = x;
                vmax = fmaxf(vmax, x);
            }
        vmax = fmaxf(vmax, __shfl_xor(vmax, 16));
        vmax = fmaxf(vmax, __shfl_xor(vmax, 32));
        if (__any((int)(vmax > m_x))) {
            float mn = fmaxf(m_x, vmax);
            float a  = __builtin_amdgcn_exp2f(m_x - mn);
            m_x = mn;
            l_x *= a;
            float ar[4];
            #pragma unroll
            for (int r = 0; r < 4; ++r) ar[r] = __shfl(a, (lane & 48) | (quad * 4 + r));
            #pragma unroll
            for (int c = 0; c < 4; ++c)
                #pragma unroll
                for (int r = 0; r < 4; ++r) o_acc[c][r] *= ar[r];
        }

        const int prow = wave * 16 + l16;
        float rs = 0.0f;
        #pragma unroll
        for (int c = 0; c < 4; ++c) {
            short4_t pw;
            #pragma unroll
            for (int r = 0; r < 4; ++r) {
                float p = __builtin_amdgcn_exp2f(sv[c][r] - m_x);
                rs += p;
                pw[r] = __builtin_bit_cast(short, (__bf16)p);
            }
            *(short4_t*)&p_lds2[swz(prow, 2 * c + (quad >> 1)) + (quad & 1) * 4] = pw;
        }
        rs += __shfl_xor(rs, 16);
        rs += __shfl_xor(rs, 32);
        l_x += rs;

        bf16x8_t pf0 = __builtin_bit_cast(bf16x8_t, *(const short8_t*)&p_lds2[swz(prow, quad)]);
        bf16x8_t pf1 = __builtin_bit_cast(bf16x8_t, *(const short8_t*)&p_lds2[swz(prow, quad + 4)]);
        #pragma unroll
        for (int c = 0; c < 4; ++c) {
            const int d = c * 16 + l16;
            bf16x8_t b0 = __builtin_bit_cast(bf16x8_t, *(const short8_t*)&vt_lds[swz(d, quad)]);
            bf16x8_t b1 = __builtin_bit_cast(bf16x8_t, *(const short8_t*)&vt_lds[swz(d, quad + 4)]);
            o_acc[c] = __builtin_amdgcn_mfma_f32_16x16x32_bf16(pf0, b0, o_acc[c], 0, 0, 0);
            o_acc[c] = __builtin_amdgcn_mfma_f32_16x16x32_bf16(pf1, b1, o_acc[c], 0, 0, 0);
        }
    }

    const int b = bh >> 4;
    const int h = bh & 15;
    #pragma unroll
    for (int r = 0; r < 4; ++r) {
        const float lr = __shfl(l_x, (lane & 48) | (quad * 4 + r));
        const float inv_l = 1.0f / fmaxf(lr, 1e-30f);
        const int row = q0 + wave * 16 + quad * 4 + r;
        float* op = outg + ((size_t)b * SEQ + row) * (NH * HD) + h * HD;
        #pragma unroll
        for (int c = 0; c < 4; ++c) {
            float val = o_acc[c][r] * inv_l;
            unsigned bits = __builtin_bit_cast(unsigned, val);
            if ((bits & 0x7F800000u) == 0x7F800000u) val = 0.0f;
            op[c * 16 + l16] = val;
        }
    }
}

extern "C" void kernel_launch(void* const* d_in, const int* in_sizes, int n_in,
                              void* d_out, int out_size, void* d_ws, size_t ws_size,
                              hipStream_t stream) {
    const float* q = (const float*)d_in[0];
    const float* k = (const float*)d_in[1];
    const float* v = (const float*)d_in[2];
    float* out = (float*)d_out;

    const size_t img_sh = (size_t)NB * NH * NT * TILE_SH;        // shorts per image
    const size_t need   = 2 * img_sh * sizeof(unsigned short);   // 33.6 MB

    if (d_ws != nullptr && ws_size >= need) {
        unsigned short* kimg = (unsigned short*)d_ws;
        unsigned short* vimg = kimg + img_sh;
        prep_kv<<<dim3(NT, NB * NH), 256, 0, stream>>>(k, v, kimg, vimg);
        fa_fwd<<<dim3(NB * NH, SEQ / BQ), 256, 0, stream>>>(q, kimg, vimg, out);
    } else {
        fa_fwd_fb<<<dim3(NB * NH, SEQ / BQ), 256, 0, stream>>>(q, k, v, out);
    }
}

// Round 10
// 186.599 us; speedup vs baseline: 1.1130x; 1.0781x over previous
//
#include <hip/hip_runtime.h>
#include <hip/hip_bf16.h>

typedef __bf16 bf16x8_t __attribute__((ext_vector_type(8)));
typedef float  f32x4_t  __attribute__((ext_vector_type(4)));
typedef short  short8_t __attribute__((ext_vector_type(8)));
typedef short  short4_t __attribute__((ext_vector_type(4)));
typedef unsigned short ushort4_t __attribute__((ext_vector_type(4)));

typedef const __attribute__((address_space(1))) unsigned int* gptr_t;
typedef __attribute__((address_space(3))) unsigned int* lptr_t;

#define NB   4
#define NH   16
#define SEQ  2048
#define HD   64
#define BQ   64
#define BKV  64
#define NT   (SEQ / BKV)          // 32 kv tiles per bh
#define TILE_SH (BKV * HD)        // 4096 shorts = 8KB per image tile

// masked score in base-2 domain: WHERE_CONST * log2(e)
#define MASK2 (-14426.950408889634f)
// softmax scale folded into Q: (1/sqrt(64)) * log2(e)
#define QSCL  (0.18033688011112042f)
// defer-max threshold (base-2 domain): skip rescale while growth <= 8 -> P <= 2^8
#define DEFER_THR 8.0f

// 64x64 bf16 tile, 128B rows, 16B-block XOR swizzle (index in shorts).
// Shared by the pre-pass (image write) and the main kernel (LDS read):
// global_load_lds copies the image LINEARLY into LDS (linear dest +
// pre-swizzled source + swizzled read).
__device__ __forceinline__ int xaddr(int row, int blk) {
    return row * 64 + (((blk ^ row) & 7) << 3);
}

// ---------------- pre-pass: fp32 K,V  ->  bf16 swizzled tile images ----------------
__global__ void __launch_bounds__(256)
prep_kv(const float* __restrict__ kg, const float* __restrict__ vg,
        unsigned short* __restrict__ kimg, unsigned short* __restrict__ vimg) {
    __shared__ alignas(16) unsigned short vstage[TILE_SH];  // V^T tile staged at image layout

    const int t   = blockIdx.x;       // kv tile
    const int bh  = blockIdx.y;
    const int tid = threadIdx.x;
    const int sr  = tid >> 4;         // owns kv rows 4sr..4sr+3
    const int cb  = tid & 15;         // d block
    const int d0  = cb * 4;

    const size_t gbase = ((size_t)bh * SEQ + (size_t)t * BKV) * HD;
    const size_t ibase = ((size_t)bh * NT + t) * TILE_SH;

    f32x4_t v4[4];
    #pragma unroll
    for (int i = 0; i < 4; ++i) {
        const int r = 4 * sr + i;
        f32x4_t k4 = *(const f32x4_t*)(kg + gbase + (size_t)r * HD + d0);
        v4[i]      = *(const f32x4_t*)(vg + gbase + (size_t)r * HD + d0);
        ushort4_t kw;
        #pragma unroll
        for (int j = 0; j < 4; ++j) kw[j] = __builtin_bit_cast(unsigned short, (__bf16)k4[j]);
        // K image write: full 128B row covered by 16 contiguous lanes -> coalesces
        *(ushort4_t*)&kimg[ibase + xaddr(r, cb >> 1) + (cb & 1) * 4] = kw;
    }
    // V^T: register-transpose 4x4 -> stage 8B chunks in LDS at IMAGE addresses
    #pragma unroll
    for (int j = 0; j < 4; ++j) {
        ushort4_t vw;
        #pragma unroll
        for (int i = 0; i < 4; ++i) vw[i] = __builtin_bit_cast(unsigned short, (__bf16)v4[i][j]);
        *(ushort4_t*)&vstage[xaddr(d0 + j, sr >> 1) + (sr & 1) * 4] = vw;
    }
    __syncthreads();
    // coalesced copyout: 32B per thread, consecutive tid -> consecutive addresses
    const int s0 = tid * 16;
    *(short8_t*)&vimg[ibase + s0]     = *(const short8_t*)&vstage[s0];
    *(short8_t*)&vimg[ibase + s0 + 8] = *(const short8_t*)&vstage[s0 + 8];
}

// async 16B global->LDS copy; lds base wave-uniform (HW adds lane*16B), g per-lane
__device__ __forceinline__ void gl16(const unsigned short* g, short* l) {
    __builtin_amdgcn_global_load_lds((gptr_t)g, (lptr_t)l, 16, 0, 0);
}

// ---------------- main kernel: images -> LDS via global_load_lds ----------------
__global__ void __launch_bounds__(256)
fa_fwd(const float* __restrict__ qg,
       const unsigned short* __restrict__ kimg,
       const unsigned short* __restrict__ vimg,
       float* __restrict__ outg) {
    __shared__ alignas(16) short kv_lds[2][2][TILE_SH];  // [buf][K/V][4096] = 32KB
    __shared__ alignas(16) short p_lds[64 * 64];         // P bf16, 8KB, same swizzle

    const int tid  = threadIdx.x;
    const int wave = tid >> 6;
    const int lane = tid & 63;
    const int l16  = lane & 15;
    const int quad = lane >> 4;

    // grid: x = bh (64), y = q-tile (32), reversed so heavy blocks dispatch first
    const int bh = blockIdx.x;
    const int qt = (int)gridDim.y - 1 - (int)blockIdx.y;
    const int q0 = qt * BQ;

    const float* qp = qg + (size_t)bh * SEQ * HD;
    const unsigned short* kb = kimg + (size_t)bh * NT * TILE_SH;
    const unsigned short* vb = vimg + (size_t)bh * NT * TILE_SH;

    // ---- Q fragments (B-operand in swapped QK^T): q=l16-row, d=quad*8+j ----
    bf16x8_t qf0, qf1;
    {
        const float* qr = qp + (size_t)(q0 + wave * 16 + l16) * HD;
        f32x4_t a0 = *(const f32x4_t*)(qr + quad * 8);
        f32x4_t a1 = *(const f32x4_t*)(qr + quad * 8 + 4);
        f32x4_t a2 = *(const f32x4_t*)(qr + 32 + quad * 8);
        f32x4_t a3 = *(const f32x4_t*)(qr + 32 + quad * 8 + 4);
        #pragma unroll
        for (int j = 0; j < 4; ++j) {
            qf0[j]     = (__bf16)(a0[j] * QSCL);
            qf0[4 + j] = (__bf16)(a1[j] * QSCL);
            qf1[j]     = (__bf16)(a2[j] * QSCL);
            qf1[4 + j] = (__bf16)(a3[j] * QSCL);
        }
    }

    f32x4_t o_acc[4];
    const f32x4_t zero4 = {0.0f, 0.0f, 0.0f, 0.0f};
    #pragma unroll
    for (int c = 0; c < 4; ++c) o_acc[c] = zero4;
    float m_x = MASK2;
    float l_x = 0.0f;     // per-lane PARTIAL row sum; cross-quad reduce in epilogue

    // staging: 2 rounds x (K,V) of 16B per thread; image is already LDS-layout
    auto stage = [&](int buf, int t) {
        const unsigned short* kg_ = kb + (size_t)t * TILE_SH;
        const unsigned short* vg_ = vb + (size_t)t * TILE_SH;
        #pragma unroll
        for (int r = 0; r < 2; ++r) {
            const int loff = r * 2048 + wave * 512;      // wave-uniform (shorts)
            const int goff = loff + lane * 8;            // per-lane (shorts)
            gl16(kg_ + goff, &kv_lds[buf][0][loff]);
            gl16(vg_ + goff, &kv_lds[buf][1][loff]);
        }
    };

    const int qloc = wave * 16 + l16;   // diag-tile local q row
    const int nt = qt + 1;
    int cur = 0;

    stage(0, 0);   // prologue: tile 0 in flight

    #pragma unroll 1
    for (int t = 0; t < nt; ++t) {
        // one barrier per iter: implicit vmcnt(0) drain completes buf[cur]'s
        // global_load_lds AND guarantees buf[cur^1]'s readers (iter t-1) are done.
        __syncthreads();
        if (t + 1 < nt) stage(cur ^ 1, t + 1);   // next tile flies during compute

        const short* kt_ = kv_lds[cur][0];
        const short* vt_ = kv_lds[cur][1];

        // ---- S^T = K Q^T : D[m=kv][n=q];  kv = c*16+quad*4+r, q = l16 ----
        f32x4_t s_acc[4];
        #pragma unroll
        for (int c = 0; c < 4; ++c) s_acc[c] = zero4;
        __builtin_amdgcn_s_setprio(1);
        #pragma unroll
        for (int c = 0; c < 4; ++c) {
            const int kvrow = c * 16 + l16;
            bf16x8_t kf0 = __builtin_bit_cast(bf16x8_t, *(const short8_t*)&kt_[xaddr(kvrow, quad)]);
            bf16x8_t kf1 = __builtin_bit_cast(bf16x8_t, *(const short8_t*)&kt_[xaddr(kvrow, quad + 4)]);
            s_acc[c] = __builtin_amdgcn_mfma_f32_16x16x32_bf16(kf0, qf0, s_acc[c], 0, 0, 0);
            s_acc[c] = __builtin_amdgcn_mfma_f32_16x16x32_bf16(kf1, qf1, s_acc[c], 0, 0, 0);
        }
        __builtin_amdgcn_s_setprio(0);

        // ---- softmax slice: fully lane-local in steady state (T13 defer-max) ----
        float sv[4][4];
        const bool diag = (t == nt - 1);
        #pragma unroll
        for (int c = 0; c < 4; ++c) {
            #pragma unroll
            for (int r = 0; r < 4; ++r) {
                float x = s_acc[c][r];
                if (diag && (c * 16 + quad * 4 + r > qloc)) x = MASK2;
                sv[c][r] = x;
            }
        }
        // 4-level lane-local max tree
        float cm[4];
        #pragma unroll
        for (int c = 0; c < 4; ++c)
            cm[c] = fmaxf(fmaxf(sv[c][0], sv[c][1]), fmaxf(sv[c][2], sv[c][3]));
        const float vloc = fmaxf(fmaxf(cm[0], cm[1]), fmaxf(cm[2], cm[3]));

        // rescale ONLY when some lane's local max exceeds m+THR.
        // (row-max > m+THR  <=>  some lane's local max > m+THR, so no reduction
        //  is needed for the vote; P stays bounded by 2^THR otherwise.)
        if (__any((int)(vloc > m_x + DEFER_THR))) {
            float vr = vloc;
            vr = fmaxf(vr, __shfl_xor(vr, 16));
            vr = fmaxf(vr, __shfl_xor(vr, 32));          // true row max
            float mn = fmaxf(m_x, vr);
            float a  = __builtin_amdgcn_exp2f(m_x - mn); // arg <= 0; row-uniform
            m_x = mn;
            l_x *= a;
            float ar[4];
            #pragma unroll
            for (int r = 0; r < 4; ++r)
                ar[r] = __shfl(a, (lane & 48) | (quad * 4 + r));   // alpha of o_acc's row
            #pragma unroll
            for (int c = 0; c < 4; ++c)
                #pragma unroll
                for (int r = 0; r < 4; ++r)
                    o_acc[c][r] *= ar[r];
        }

        // ---- P = exp2(sv - m) (<= 2^THR); partial row sum; write P (8B chunks) ----
        const int prow = wave * 16 + l16;
        float rs = 0.0f;
        #pragma unroll
        for (int c = 0; c < 4; ++c) {
            short4_t pw;
            #pragma unroll
            for (int r = 0; r < 4; ++r) {
                float p = __builtin_amdgcn_exp2f(sv[c][r] - m_x);
                rs += p;
                pw[r] = __builtin_bit_cast(short, (__bf16)p);
            }
            *(short4_t*)&p_lds[xaddr(prow, 2 * c + (quad >> 1)) + (quad & 1) * 4] = pw;
        }
        l_x += rs;    // per-lane partial; cross-quad sum deferred to epilogue

        // NO barrier: P rows are written and read by the same wave (lgkmcnt orders)

        // ---- O += P V  (A = P[m=q][k=kv], B = V^T rows as B[k=kv][n=d]) ----
        bf16x8_t pf0 = __builtin_bit_cast(bf16x8_t, *(const short8_t*)&p_lds[xaddr(prow, quad)]);
        bf16x8_t pf1 = __builtin_bit_cast(bf16x8_t, *(const short8_t*)&p_lds[xaddr(prow, quad + 4)]);
        __builtin_amdgcn_s_setprio(1);
        #pragma unroll
        for (int c = 0; c < 4; ++c) {
            const int d = c * 16 + l16;
            bf16x8_t b0 = __builtin_bit_cast(bf16x8_t, *(const short8_t*)&vt_[xaddr(d, quad)]);
            bf16x8_t b1 = __builtin_bit_cast(bf16x8_t, *(const short8_t*)&vt_[xaddr(d, quad + 4)]);
            o_acc[c] = __builtin_amdgcn_mfma_f32_16x16x32_bf16(pf0, b0, o_acc[c], 0, 0, 0);
            o_acc[c] = __builtin_amdgcn_mfma_f32_16x16x32_bf16(pf1, b1, o_acc[c], 0, 0, 0);
        }
        __builtin_amdgcn_s_setprio(0);

        cur ^= 1;
    }

    // ---- epilogue: finish l reduction, O / l, fp32 store ----
    l_x += __shfl_xor(l_x, 16);
    l_x += __shfl_xor(l_x, 32);
    const int b = bh >> 4;
    const int h = bh & 15;
    #pragma unroll
    for (int r = 0; r < 4; ++r) {
        const float lr = __shfl(l_x, (lane & 48) | (quad * 4 + r));
        const float inv_l = 1.0f / fmaxf(lr, 1e-30f);
        const int row = q0 + wave * 16 + quad * 4 + r;
        float* op = outg + ((size_t)b * SEQ + row) * (NH * HD) + h * HD;
        #pragma unroll
        for (int c = 0; c < 4; ++c) {
            float val = o_acc[c][r] * inv_l;
            unsigned bits = __builtin_bit_cast(unsigned, val);
            if ((bits & 0x7F800000u) == 0x7F800000u) val = 0.0f;  // scrub inf/NaN
            op[c * 16 + l16] = val;
        }
    }
}

// ---------------- fallback (no workspace): proven R2 kernel, fp32 staging ----------------
#define LSTR 72
__device__ __forceinline__ int swz(int rowi, int blk) {
    return rowi * LSTR + (((blk) ^ (rowi >> 3)) & 7) * 8;
}

__global__ void __launch_bounds__(256)
fa_fwd_fb(const float* __restrict__ qg,
          const float* __restrict__ kg,
          const float* __restrict__ vg,
          float* __restrict__ outg) {
    __shared__ alignas(16) short k_lds[BKV * LSTR];
    __shared__ alignas(16) short vt_lds[HD * LSTR];
    __shared__ alignas(16) short p_lds2[BQ * LSTR];

    const int tid  = threadIdx.x;
    const int wave = tid >> 6;
    const int lane = tid & 63;
    const int l16  = lane & 15;
    const int quad = lane >> 4;

    const int bh = blockIdx.x;
    const int qt = (int)gridDim.y - 1 - (int)blockIdx.y;
    const int q0 = qt * BQ;

    const size_t base = (size_t)bh * SEQ * HD;
    const float* qp = qg + base;
    const float* kp = kg + base;
    const float* vp = vg + base;

    bf16x8_t qf0, qf1;
    {
        const float* qr = qp + (size_t)(q0 + wave * 16 + l16) * HD;
        f32x4_t a0 = *(const f32x4_t*)(qr + quad * 8);
        f32x4_t a1 = *(const f32x4_t*)(qr + quad * 8 + 4);
        f32x4_t a2 = *(const f32x4_t*)(qr + 32 + quad * 8);
        f32x4_t a3 = *(const f32x4_t*)(qr + 32 + quad * 8 + 4);
        #pragma unroll
        for (int j = 0; j < 4; ++j) {
            qf0[j]     = (__bf16)(a0[j] * QSCL);
            qf0[4 + j] = (__bf16)(a1[j] * QSCL);
            qf1[j]     = (__bf16)(a2[j] * QSCL);
            qf1[4 + j] = (__bf16)(a3[j] * QSCL);
        }
    }

    f32x4_t o_acc[4];
    const f32x4_t zero4 = {0.0f, 0.0f, 0.0f, 0.0f};
    #pragma unroll
    for (int c = 0; c < 4; ++c) o_acc[c] = zero4;
    float m_x = MASK2, l_x = 0.0f;

    const int sr = tid >> 4;
    const int cb = tid & 15;
    const int d0 = cb * 4;
    f32x4_t kreg[4], vreg[4];

    auto issue = [&](int kt0) {
        const float* kr = kp + (size_t)(kt0 + 4 * sr) * HD + d0;
        const float* vr = vp + (size_t)(kt0 + 4 * sr) * HD + d0;
        #pragma unroll
        for (int i = 0; i < 4; ++i) {
            kreg[i] = *(const f32x4_t*)(kr + i * HD);
            vreg[i] = *(const f32x4_t*)(vr + i * HD);
        }
    };
    auto stg = [&]() {
        #pragma unroll
        for (int i = 0; i < 4; ++i) {
            const int r0 = 4 * sr + i;
            short4_t kw;
            #pragma unroll
            for (int j = 0; j < 4; ++j) kw[j] = __builtin_bit_cast(short, (__bf16)kreg[i][j]);
            *(short4_t*)&k_lds[swz(r0, cb >> 1) + (cb & 1) * 4] = kw;
        }
        #pragma unroll
        for (int j = 0; j < 4; ++j) {
            short4_t vw;
            #pragma unroll
            for (int i = 0; i < 4; ++i) vw[i] = __builtin_bit_cast(short, (__bf16)vreg[i][j]);
            *(short4_t*)&vt_lds[swz(d0 + j, sr >> 1) + (sr & 1) * 4] = vw;
        }
    };

    issue(0);
    const int qloc = wave * 16 + l16;
    const int nt = qt + 1;
    for (int t = 0; t < nt; ++t) {
        __syncthreads();
        stg();
        __syncthreads();
        if (t + 1 < nt) issue((t + 1) * BKV);

        f32x4_t s_acc[4];
        #pragma unroll
        for (int c = 0; c < 4; ++c) s_acc[c] = zero4;
        #pragma unroll
        for (int c = 0; c < 4; ++c) {
            const int kvrow = c * 16 + l16;
            bf16x8_t kf0 = __builtin_bit_cast(bf16x8_t, *(const short8_t*)&k_lds[swz(kvrow, quad)]);
            bf16x8_t kf1 = __builtin_bit_cast(bf16x8_t, *(const short8_t*)&k_lds[swz(kvrow, quad + 4)]);
            s_acc[c] = __builtin_amdgcn_mfma_f32_16x16x32_bf16(kf0, qf0, s_acc[c], 0, 0, 0);
            s_acc[c] = __builtin_amdgcn_mfma_f32_16x16x32_bf16(kf1, qf1, s_acc[c], 0, 0, 0);
        }

        float sv[4][4];
        float vmax = MASK2;
        const bool diag = (t == nt - 1);
        #pragma unroll
        for (int c = 0; c < 4; ++c)
            #pragma unroll
            for (int r = 0; r < 4; ++r) {
                float x = s_acc[c][r];
                if (diag && (c * 16 + quad * 4 + r > qloc)) x = MASK2;
                sv[c][r] = x;
                vmax = fmaxf(vmax, x);
            }
        vmax = fmaxf(vmax, __shfl_xor(vmax, 16));
        vmax = fmaxf(vmax, __shfl_xor(vmax, 32));
        if (__any((int)(vmax > m_x))) {
            float mn = fmaxf(m_x, vmax);
            float a  = __builtin_amdgcn_exp2f(m_x - mn);
            m_x = mn;
            l_x *= a;
            float ar[4];
            #pragma unroll
            for (int r = 0; r < 4; ++r) ar[r] = __shfl(a, (lane & 48) | (quad * 4 + r));
            #pragma unroll
            for (int c = 0; c < 4; ++c)
                #pragma unroll
                for (int r = 0; r < 4; ++r) o_acc[c][r] *= ar[r];
        }

        const int prow = wave * 16 + l16;
        float rs = 0.0f;
        #pragma unroll
        for (int c = 0; c < 4; ++c) {
            short4_t pw;
            #pragma unroll
            for (int r = 0; r < 4; ++r) {
                float p = __builtin_amdgcn_exp2f(sv[c][r] - m_x);
                rs += p;
                pw[r] = __builtin_bit_cast(short, (__bf16)p);
            }
            *(short4_t*)&p_lds2[swz(prow, 2 * c + (quad >> 1)) + (quad & 1) * 4] = pw;
        }
        rs += __shfl_xor(rs, 16);
        rs += __shfl_xor(rs, 32);
        l_x += rs;

        bf16x8_t pf0 = __builtin_bit_cast(bf16x8_t, *(const short8_t*)&p_lds2[swz(prow, quad)]);
        bf16x8_t pf1 = __builtin_bit_cast(bf16x8_t, *(const short8_t*)&p_lds2[swz(prow, quad + 4)]);
        #pragma unroll
        for (int c = 0; c < 4; ++c) {
            const int d = c * 16 + l16;
            bf16x8_t b0 = __builtin_bit_cast(bf16x8_t, *(const short8_t*)&vt_lds[swz(d, quad)]);
            bf16x8_t b1 = __builtin_bit_cast(bf16x8_t, *(const short8_t*)&vt_lds[swz(d, quad + 4)]);
            o_acc[c] = __builtin_amdgcn_mfma_f32_16x16x32_bf16(pf0, b0, o_acc[c], 0, 0, 0);
            o_acc[c] = __builtin_amdgcn_mfma_f32_16x16x32_bf16(pf1, b1, o_acc[c], 0, 0, 0);
        }
    }

    const int b = bh >> 4;
    const int h = bh & 15;
    #pragma unroll
    for (int r = 0; r < 4; ++r) {
        const float lr = __shfl(l_x, (lane & 48) | (quad * 4 + r));
        const float inv_l = 1.0f / fmaxf(lr, 1e-30f);
        const int row = q0 + wave * 16 + quad * 4 + r;
        float* op = outg + ((size_t)b * SEQ + row) * (NH * HD) + h * HD;
        #pragma unroll
        for (int c = 0; c < 4; ++c) {
            float val = o_acc[c][r] * inv_l;
            unsigned bits = __builtin_bit_cast(unsigned, val);
            if ((bits & 0x7F800000u) == 0x7F800000u) val = 0.0f;
            op[c * 16 + l16] = val;
        }
    }
}

extern "C" void kernel_launch(void* const* d_in, const int* in_sizes, int n_in,
                              void* d_out, int out_size, void* d_ws, size_t ws_size,
                              hipStream_t stream) {
    const float* q = (const float*)d_in[0];
    const float* k = (const float*)d_in[1];
    const float* v = (const float*)d_in[2];
    float* out = (float*)d_out;

    const size_t img_sh = (size_t)NB * NH * NT * TILE_SH;        // shorts per image
    const size_t need   = 2 * img_sh * sizeof(unsigned short);   // 33.6 MB

    if (d_ws != nullptr && ws_size >= need) {
        unsigned short* kimg = (unsigned short*)d_ws;
        unsigned short* vimg = kimg + img_sh;
        prep_kv<<<dim3(NT, NB * NH), 256, 0, stream>>>(k, v, kimg, vimg);
        fa_fwd<<<dim3(NB * NH, SEQ / BQ), 256, 0, stream>>>(q, kimg, vimg, out);
    } else {
        fa_fwd_fb<<<dim3(NB * NH, SEQ / BQ), 256, 0, stream>>>(q, k, v, out);
    }
}